// Round 1
// baseline (546.427 us; speedup 1.0000x reference)
//
#include <hip/hip_runtime.h>
#include <hip/hip_bf16.h>

// AutoregressiveRoutingHead: B=65536, L=8, LATENT=256, HID=128, NTOK=5
// Strategy:
//  K1: G[tok][j] = emb[tok]@W_ih[j] + b_ih[j] + (j<512 ? b_hh[j] : 0)   (6x768 f32, in d_ws)
//  K2: W_hh (768x256 f32) -> bf16, rearranged fragment-linear for mfma_32x32x16 A-frags
//  K3 (main): 1024 blocks x 512 threads; block owns 64 batch rows.
//      gh^T = W_hh * h^T via MFMA (M=gates, N=batch). Wave w owns gate rows
//      {g*256+32w..+32} so (r,z,n) triples are lane-local -> in-register GRU update.
//      h master fp32 in registers; bf16 copy in LDS (fragment-linear, conflict-free).

typedef __attribute__((ext_vector_type(8)))  __bf16 bf16x8;
typedef __attribute__((ext_vector_type(4)))  __bf16 bf16x4;
typedef __attribute__((ext_vector_type(16))) float  f32x16;

__device__ __forceinline__ float sigm(float x) {
    return __builtin_amdgcn_rcpf(1.f + __expf(-x));
}
__device__ __forceinline__ float tanh_fast(float x) {
    float ax = fabsf(x);
    float u  = __expf(-2.f * ax);
    float t  = (1.f - u) * __builtin_amdgcn_rcpf(1.f + u);
    return copysignf(t, x);
}
__device__ __forceinline__ float f4get(const float4& v, int i) {
    return i == 0 ? v.x : i == 1 ? v.y : i == 2 ? v.z : v.w;
}

// ---------------- K1: gi table ----------------
__global__ void k_gtable(const float* __restrict__ emb, const float* __restrict__ W_ih,
                         const float* __restrict__ b_ih, const float* __restrict__ b_hh,
                         float* __restrict__ G) {
    int tok = blockIdx.x;      // 0..5
    int j   = threadIdx.x;     // 0..767
    const float4* e4 = (const float4*)(emb + tok * 128);
    const float4* w4 = (const float4*)(W_ih + (size_t)j * 128);
    float s = 0.f;
#pragma unroll
    for (int k = 0; k < 32; ++k) {
        float4 a = e4[k], b = w4[k];
        s += a.x * b.x + a.y * b.y + a.z * b.z + a.w * b.w;
    }
    s += b_ih[j];
    if (j < 512) s += b_hh[j];   // fold b_hh into r,z gate pre-activations
    G[tok * 768 + j] = s;
}

// ---------------- K2: W_hh -> bf16 fragment-linear ----------------
// Frag (g,w,kc): A[m][k], m = g*256 + 32*w + (lane&31), k = kc*16 + (lane>>5)*8 + j
__global__ void k_wfrag(const float* __restrict__ Whh, __bf16* __restrict__ Wg) {
    int u = blockIdx.x * 256 + threadIdx.x;   // 0..24575
    int lane = u & 63;
    int kc   = (u >> 6) & 15;
    int w    = (u >> 10) & 7;
    int g    = u >> 13;
    int row  = g * 256 + w * 32 + (lane & 31);
    int k0   = kc * 16 + (lane >> 5) * 8;
    const float* src = Whh + (size_t)row * 256 + k0;
    bf16x8 v;
#pragma unroll
    for (int j = 0; j < 8; ++j) v[j] = (__bf16)src[j];
    *(bf16x8*)(Wg + (size_t)u * 8) = v;
}

// ---------------- K3: main recurrent kernel ----------------
#define LOADA(dst, g_, kc_) dst = *(const bf16x8*)(Wg + ((((size_t)((g_)*8 + w)) * 16 + (kc_)) * 64 + lane) * 8)
#define LOADB(dst, nt_, kc_) dst = *(const bf16x8*)&h_lds[nt_][kc_][lane][0]

__global__ __launch_bounds__(512) void k_main(
    const float* __restrict__ latent, const int* __restrict__ tgt,
    const float* __restrict__ Gtab, const __bf16* __restrict__ Wg,
    const float* __restrict__ b_hh, const float* __restrict__ Wout,
    const float* __restrict__ bout, float* __restrict__ out) {

    __shared__ __bf16 h_lds[2][16][64][8];   // [nt][kc][slot=lane][j] : 32 KB, frag-linear
    __shared__ int    tok_lds[64 * 9];       // padded stride 9 (bank-conflict-free)
    __shared__ float  bhn_lds[256];          // b_hh[512:768]
    __shared__ float  wout_lds[5 * 260];     // W_out padded stride 260
    __shared__ float  red[8][64][5];         // logit partials per wave

    const int tid  = threadIdx.x;
    const int lane = tid & 63;
    const int w    = tid >> 6;       // wave 0..7
    const int hk   = lane >> 5;      // k-half
    const int bn   = lane & 31;      // batch-local within Ntile
    const int row0 = blockIdx.x * 64;

    // ---- stage small tables ----
    {
        int b = tid >> 3, t = tid & 7;
        tok_lds[b * 9 + t] = (t == 0) ? 5 : tgt[(size_t)(row0 + b) * 8 + t - 1];
    }
    if (tid < 256) bhn_lds[tid] = b_hh[512 + tid];
    for (int i = tid; i < 5 * 256; i += 512) wout_lds[(i >> 8) * 260 + (i & 255)] = Wout[i];

    // ---- init h registers (fp32 master) + bf16 LDS copy ----
    float h[2][16];
#pragma unroll
    for (int nt = 0; nt < 2; ++nt) {
        int grow = row0 + nt * 32 + bn;
#pragma unroll
        for (int q = 0; q < 4; ++q) {
            int cb = w * 32 + q * 8 + hk * 4;   // gate-col base for reg&3==0
            float4 hv = *(const float4*)(latent + (size_t)grow * 256 + cb);
            h[nt][4 * q + 0] = hv.x; h[nt][4 * q + 1] = hv.y;
            h[nt][4 * q + 2] = hv.z; h[nt][4 * q + 3] = hv.w;
            bf16x4 hb;
            hb[0] = (__bf16)hv.x; hb[1] = (__bf16)hv.y;
            hb[2] = (__bf16)hv.z; hb[3] = (__bf16)hv.w;
            *(bf16x4*)&h_lds[nt][2 * w + (q >> 1)][(q & 1) * 32 + bn][4 * hk] = hb;
        }
    }
    __syncthreads();

    for (int t = 0; t < 8; ++t) {
        // ---- MFMA phase: acc[g][nt] += Wfrag(g,kc) * hfrag(nt,kc) ----
        f32x16 acc[3][2];
        {
            f32x16 zz;
#pragma unroll
            for (int i = 0; i < 16; ++i) zz[i] = 0.f;
#pragma unroll
            for (int g = 0; g < 3; ++g)
#pragma unroll
                for (int nt = 0; nt < 2; ++nt) acc[g][nt] = zz;
        }
        {
            bf16x8 a0, a1, a2, b0, b1;
            LOADA(a0, 0, 0); LOADA(a1, 1, 0); LOADA(a2, 2, 0);
            LOADB(b0, 0, 0); LOADB(b1, 1, 0);
#pragma unroll
            for (int kc = 0; kc < 16; ++kc) {
                bf16x8 na0, na1, na2, nb0, nb1;
                if (kc < 15) {
                    LOADA(na0, 0, kc + 1); LOADA(na1, 1, kc + 1); LOADA(na2, 2, kc + 1);
                    LOADB(nb0, 0, kc + 1); LOADB(nb1, 1, kc + 1);
                }
                acc[0][0] = __builtin_amdgcn_mfma_f32_32x32x16_bf16(a0, b0, acc[0][0], 0, 0, 0);
                acc[0][1] = __builtin_amdgcn_mfma_f32_32x32x16_bf16(a0, b1, acc[0][1], 0, 0, 0);
                acc[1][0] = __builtin_amdgcn_mfma_f32_32x32x16_bf16(a1, b0, acc[1][0], 0, 0, 0);
                acc[1][1] = __builtin_amdgcn_mfma_f32_32x32x16_bf16(a1, b1, acc[1][1], 0, 0, 0);
                acc[2][0] = __builtin_amdgcn_mfma_f32_32x32x16_bf16(a2, b0, acc[2][0], 0, 0, 0);
                acc[2][1] = __builtin_amdgcn_mfma_f32_32x32x16_bf16(a2, b1, acc[2][1], 0, 0, 0);
                a0 = na0; a1 = na1; a2 = na2; b0 = nb0; b1 = nb1;
            }
        }
        __syncthreads();   // all h_lds reads done block-wide

        // ---- combine: GRU gate update, fully lane-local ----
        // acc layout: col(batch) = lane&31 (+nt*32), row rr = (reg&3)+8*(reg>>2)+4*hk,
        // gate-col colc = 32w + rr.
#pragma unroll
        for (int nt = 0; nt < 2; ++nt) {
            int tok = tok_lds[(nt * 32 + bn) * 9 + t];
            const float* Gt = Gtab + tok * 768;
#pragma unroll
            for (int q = 0; q < 4; ++q) {
                int cb = w * 32 + q * 8 + hk * 4;
                float4 g0 = *(const float4*)(Gt + cb);          // i_r + b_ih + b_hh
                float4 g1 = *(const float4*)(Gt + 256 + cb);    // i_z + b_ih + b_hh
                float4 g2 = *(const float4*)(Gt + 512 + cb);    // i_n + b_ih
                float4 bh = *(const float4*)&bhn_lds[cb];       // b_hh (n gate)
                bf16x4 hb;
#pragma unroll
                for (int i = 0; i < 4; ++i) {
                    int r = 4 * q + i;
                    float ar = acc[0][nt][r] + f4get(g0, i);
                    float az = acc[1][nt][r] + f4get(g1, i);
                    float hn = acc[2][nt][r] + f4get(bh, i);
                    float rg = sigm(ar);
                    float zg = sigm(az);
                    float ng = tanh_fast(f4get(g2, i) + rg * hn);
                    float hv = h[nt][r];
                    hv = ng + zg * (hv - ng);
                    h[nt][r] = hv;
                    hb[i] = (__bf16)hv;
                }
                *(bf16x4*)&h_lds[nt][2 * w + (q >> 1)][(q & 1) * 32 + bn][4 * hk] = hb;
            }
        }

        // ---- logits partials from fp32 h registers ----
        float p[2][5];
#pragma unroll
        for (int nt = 0; nt < 2; ++nt)
#pragma unroll
            for (int o = 0; o < 5; ++o) p[nt][o] = 0.f;
#pragma unroll
        for (int q = 0; q < 4; ++q) {
            int cb = w * 32 + q * 8 + hk * 4;
#pragma unroll
            for (int o = 0; o < 5; ++o) {
                float4 wv = *(const float4*)&wout_lds[o * 260 + cb];
#pragma unroll
                for (int i = 0; i < 4; ++i) {
                    p[0][o] += f4get(wv, i) * h[0][4 * q + i];
                    p[1][o] += f4get(wv, i) * h[1][4 * q + i];
                }
            }
        }
#pragma unroll
        for (int nt = 0; nt < 2; ++nt)
#pragma unroll
            for (int o = 0; o < 5; ++o) {
                float v = p[nt][o] + __shfl_xor(p[nt][o], 32, 64);
                if (hk == 0) red[w][nt * 32 + bn][o] = v;
            }
        __syncthreads();

        // ---- final reduce across waves + store ----
        if (tid < 320) {
            int b = tid / 5, o = tid - 5 * b;
            float s = bout[o];
#pragma unroll
            for (int ww = 0; ww < 8; ++ww) s += red[ww][b][o];
            out[((size_t)(row0 + b) * 8 + t) * 5 + o] = s;
        }
        // next step's h_lds reads are protected by the pre-reduce barrier;
        // next step's red writes are protected by the post-MFMA barrier.
    }
}

extern "C" void kernel_launch(void* const* d_in, const int* in_sizes, int n_in,
                              void* d_out, int out_size, void* d_ws, size_t ws_size,
                              hipStream_t stream) {
    const float* latent = (const float*)d_in[0];
    const int*   tgt    = (const int*)d_in[1];
    const float* emb    = (const float*)d_in[2];
    const float* W_ih   = (const float*)d_in[3];
    const float* W_hh   = (const float*)d_in[4];
    const float* b_ih   = (const float*)d_in[5];
    const float* b_hh   = (const float*)d_in[6];
    const float* W_out  = (const float*)d_in[7];
    const float* b_out  = (const float*)d_in[8];
    float* out = (float*)d_out;

    float*  Gtab = (float*)d_ws;                       // 6*768*4   = 18432 B
    __bf16* Wg   = (__bf16*)((char*)d_ws + 18432);     // 768*256*2 = 393216 B

    k_gtable<<<6, 768, 0, stream>>>(emb, W_ih, b_ih, b_hh, Gtab);
    k_wfrag<<<96, 256, 0, stream>>>(W_hh, Wg);
    k_main<<<1024, 512, 0, stream>>>(latent, tgt, Gtab, Wg, b_hh, W_out, b_out, out);
}